// Round 6
// baseline (1136.814 us; speedup 1.0000x reference)
//
#include <hip/hip_runtime.h>

// ---------------- degree ----------------
__global__ void deg_kernel(const int* __restrict__ dst, int* __restrict__ deg, int E) {
    int e = blockIdx.x * blockDim.x + threadIdx.x;
    if (e < E) atomicAdd(&deg[dst[e]], 1);
}

// ---------------- scan1 (+ fused dinv) ----------------
__global__ void scan1_kernel(const int* __restrict__ deg, int* __restrict__ rowstart,
                             int* __restrict__ blockSums, float* __restrict__ dinv, int n) {
    __shared__ int tmp[256];
    int t = threadIdx.x;
    int i = blockIdx.x * 256 + t;
    int v = (i < n) ? deg[i] : 0;
    if (i < n) dinv[i] = rsqrtf((float)(v + 1));  // +1 = self loop
    tmp[t] = v;
    __syncthreads();
#pragma unroll
    for (int off = 1; off < 256; off <<= 1) {
        int add = (t >= off) ? tmp[t - off] : 0;
        __syncthreads();
        tmp[t] += add;
        __syncthreads();
    }
    if (i < n) rowstart[i] = tmp[t] - v;
    if (t == 255) blockSums[blockIdx.x] = tmp[255];
}

__global__ void scan2_kernel(int* __restrict__ blockSums, int nb) {
    __shared__ int tmp[512];
    int t = threadIdx.x;
    int v = (t < nb) ? blockSums[t] : 0;
    tmp[t] = v;
    __syncthreads();
#pragma unroll
    for (int off = 1; off < 512; off <<= 1) {
        int add = (t >= off) ? tmp[t - off] : 0;
        __syncthreads();
        tmp[t] += add;
        __syncthreads();
    }
    if (t < nb) blockSums[t] = tmp[t] - v;
}

__global__ void scan3_kernel(int* __restrict__ rowstart, const int* __restrict__ blockSums,
                             int* __restrict__ cursor, int n) {
    int i = blockIdx.x * blockDim.x + threadIdx.x;
    if (i < n) {
        int r = rowstart[i] + blockSums[i >> 8];
        rowstart[i] = r;
        cursor[i] = r;
    }
}

// ---------------- counting-sort edges by dst; pack (src, weight) ----------------
__global__ void sort_kernel(const int* __restrict__ src, const int* __restrict__ dst,
                            const float* __restrict__ dinv, int* __restrict__ cursor,
                            int2* __restrict__ edgeSorted, int E) {
    int e = blockIdx.x * blockDim.x + threadIdx.x;
    if (e < E) {
        int s = src[e], d = dst[e];
        int pos = atomicAdd(&cursor[d], 1);
        int2 p;
        p.x = s;
        p.y = __float_as_int(dinv[s] * dinv[d]);
        edgeSorted[pos] = p;
    }
}

// ---------------- GEMM1: h1[N,128] = x[N,128] @ W1[128,128] ----------------
// 256 threads, tile 64 nodes x 128 cols, register tile 8x4, k-step 4
__global__ __launch_bounds__(256) void gemm_nk128(const float* __restrict__ x,
                                                  const float* __restrict__ W,
                                                  float* __restrict__ h, int n) {
    __shared__ float xs[64][128];
    int t = threadIdx.x;
    int node0 = blockIdx.x * 64;
#pragma unroll
    for (int i = 0; i < 8; i++) {
        int fi = t + 256 * i;            // 0..2047 float4 slots
        int row = fi >> 5, cv = fi & 31;
        float4 v = make_float4(0.f, 0.f, 0.f, 0.f);
        if (node0 + row < n) v = ((const float4*)x)[(size_t)(node0 + row) * 32 + cv];
        ((float4*)(&xs[0][0]))[fi] = v;
    }
    __syncthreads();

    int tx = t & 31, ty = t >> 5;
    int c0 = tx * 4;
    float acc[8][4];
#pragma unroll
    for (int i = 0; i < 8; i++)
#pragma unroll
        for (int j = 0; j < 4; j++) acc[i][j] = 0.f;

    for (int k = 0; k < 128; k += 4) {
        float4 w0 = *(const float4*)(W + (k + 0) * 128 + c0);
        float4 w1 = *(const float4*)(W + (k + 1) * 128 + c0);
        float4 w2 = *(const float4*)(W + (k + 2) * 128 + c0);
        float4 w3 = *(const float4*)(W + (k + 3) * 128 + c0);
#pragma unroll
        for (int i = 0; i < 8; i++) {
            float4 xv = *(const float4*)(&xs[ty + 8 * i][k]);
            acc[i][0] += xv.x * w0.x + xv.y * w1.x + xv.z * w2.x + xv.w * w3.x;
            acc[i][1] += xv.x * w0.y + xv.y * w1.y + xv.z * w2.y + xv.w * w3.y;
            acc[i][2] += xv.x * w0.z + xv.y * w1.z + xv.z * w2.z + xv.w * w3.z;
            acc[i][3] += xv.x * w0.w + xv.y * w1.w + xv.z * w2.w + xv.w * w3.w;
        }
    }
#pragma unroll
    for (int i = 0; i < 8; i++) {
        int node = node0 + ty + 8 * i;
        if (node < n)
            *(float4*)(h + (size_t)node * 128 + c0) =
                make_float4(acc[i][0], acc[i][1], acc[i][2], acc[i][3]);
    }
}

// ---------------- gather1: h2 = relu(agg(h1) + b1) ----------------
// one wave per node (lane = 2 cols, float2), 4 nodes/block, no barrier; 8x unroll
__global__ __launch_bounds__(256) void gather1_kernel(
        const int2* __restrict__ eS, const int* __restrict__ rowstart,
        const int* __restrict__ deg, const float* __restrict__ dinv,
        const float* __restrict__ h1, const float* __restrict__ b1,
        float* __restrict__ h2, int n) {
    int t = threadIdx.x;
    int w = t >> 6, lane = t & 63;
    int g = blockIdx.x * 4 + w;
    if (g >= n) return;

    float di = dinv[g];
    float w0 = di * di;
    float2 v = ((const float2*)(h1 + (size_t)g * 128))[lane];
    float2 acc = make_float2(w0 * v.x, w0 * v.y);
    int beg = rowstart[g], end = beg + deg[g];
    int e = beg;
    for (; e + 8 <= end; e += 8) {
        int2 p0 = eS[e], p1 = eS[e+1], p2 = eS[e+2], p3 = eS[e+3];
        int2 p4 = eS[e+4], p5 = eS[e+5], p6 = eS[e+6], p7 = eS[e+7];
        float2 u0 = ((const float2*)(h1 + (size_t)p0.x * 128))[lane];
        float2 u1 = ((const float2*)(h1 + (size_t)p1.x * 128))[lane];
        float2 u2 = ((const float2*)(h1 + (size_t)p2.x * 128))[lane];
        float2 u3 = ((const float2*)(h1 + (size_t)p3.x * 128))[lane];
        float2 u4 = ((const float2*)(h1 + (size_t)p4.x * 128))[lane];
        float2 u5 = ((const float2*)(h1 + (size_t)p5.x * 128))[lane];
        float2 u6 = ((const float2*)(h1 + (size_t)p6.x * 128))[lane];
        float2 u7 = ((const float2*)(h1 + (size_t)p7.x * 128))[lane];
        acc.x += __int_as_float(p0.y) * u0.x; acc.y += __int_as_float(p0.y) * u0.y;
        acc.x += __int_as_float(p1.y) * u1.x; acc.y += __int_as_float(p1.y) * u1.y;
        acc.x += __int_as_float(p2.y) * u2.x; acc.y += __int_as_float(p2.y) * u2.y;
        acc.x += __int_as_float(p3.y) * u3.x; acc.y += __int_as_float(p3.y) * u3.y;
        acc.x += __int_as_float(p4.y) * u4.x; acc.y += __int_as_float(p4.y) * u4.y;
        acc.x += __int_as_float(p5.y) * u5.x; acc.y += __int_as_float(p5.y) * u5.y;
        acc.x += __int_as_float(p6.y) * u6.x; acc.y += __int_as_float(p6.y) * u6.y;
        acc.x += __int_as_float(p7.y) * u7.x; acc.y += __int_as_float(p7.y) * u7.y;
    }
    for (; e < end; e++) {
        int2 p = eS[e];
        float2 u = ((const float2*)(h1 + (size_t)p.x * 128))[lane];
        float wf = __int_as_float(p.y);
        acc.x += wf * u.x; acc.y += wf * u.y;
    }
    float2 b = ((const float2*)b1)[lane];
    acc.x = fmaxf(acc.x + b.x, 0.f);
    acc.y = fmaxf(acc.y + b.y, 0.f);
    ((float2*)(h2 + (size_t)g * 128))[lane] = acc;
}

// ---------------- GEMM2: h3[N,64] = h2[N,128] @ W2[128,64] ----------------
__global__ __launch_bounds__(256) void gemm_nk64(const float* __restrict__ x,
                                                 const float* __restrict__ W,
                                                 float* __restrict__ h, int n) {
    __shared__ float xs[32][128];
    int t = threadIdx.x;
    int node0 = blockIdx.x * 32;
#pragma unroll
    for (int i = 0; i < 4; i++) {
        int fi = t + 256 * i;
        int row = fi >> 5, cv = fi & 31;
        float4 v = make_float4(0.f, 0.f, 0.f, 0.f);
        if (node0 + row < n) v = ((const float4*)x)[(size_t)(node0 + row) * 32 + cv];
        ((float4*)(&xs[0][0]))[fi] = v;
    }
    __syncthreads();

    int tx = t & 15, ty = t >> 4;
    int c0 = tx * 4;
    float acc[2][4];
#pragma unroll
    for (int i = 0; i < 2; i++)
#pragma unroll
        for (int j = 0; j < 4; j++) acc[i][j] = 0.f;

    for (int k = 0; k < 128; k += 4) {
        float4 w0 = *(const float4*)(W + (k + 0) * 64 + c0);
        float4 w1 = *(const float4*)(W + (k + 1) * 64 + c0);
        float4 w2 = *(const float4*)(W + (k + 2) * 64 + c0);
        float4 w3 = *(const float4*)(W + (k + 3) * 64 + c0);
#pragma unroll
        for (int i = 0; i < 2; i++) {
            float4 xv = *(const float4*)(&xs[ty + 16 * i][k]);
            acc[i][0] += xv.x * w0.x + xv.y * w1.x + xv.z * w2.x + xv.w * w3.x;
            acc[i][1] += xv.x * w0.y + xv.y * w1.y + xv.z * w2.y + xv.w * w3.y;
            acc[i][2] += xv.x * w0.z + xv.y * w1.z + xv.z * w2.z + xv.w * w3.z;
            acc[i][3] += xv.x * w0.w + xv.y * w1.w + xv.z * w2.w + xv.w * w3.w;
        }
    }
#pragma unroll
    for (int i = 0; i < 2; i++) {
        int node = node0 + ty + 16 * i;
        if (node < n)
            *(float4*)(h + (size_t)node * 64 + c0) =
                make_float4(acc[i][0], acc[i][1], acc[i][2], acc[i][3]);
    }
}

// ---------------- gather2: out = agg(h3) + b2 ; one wave per node, lane = col ----------------
__global__ __launch_bounds__(256) void gather2_kernel(
        const int2* __restrict__ eS, const int* __restrict__ rowstart,
        const int* __restrict__ deg, const float* __restrict__ dinv,
        const float* __restrict__ h3, const float* __restrict__ b2,
        float* __restrict__ out, int n) {
    int t = threadIdx.x;
    int w = t >> 6, lane = t & 63;
    int g = blockIdx.x * 4 + w;
    if (g >= n) return;
    float di = dinv[g];
    float w0 = di * di;
    float acc = w0 * h3[(size_t)g * 64 + lane];
    int beg = rowstart[g], end = beg + deg[g];
    int e = beg;
    for (; e + 8 <= end; e += 8) {
        int2 p0 = eS[e], p1 = eS[e+1], p2 = eS[e+2], p3 = eS[e+3];
        int2 p4 = eS[e+4], p5 = eS[e+5], p6 = eS[e+6], p7 = eS[e+7];
        float u0 = h3[(size_t)p0.x * 64 + lane];
        float u1 = h3[(size_t)p1.x * 64 + lane];
        float u2 = h3[(size_t)p2.x * 64 + lane];
        float u3 = h3[(size_t)p3.x * 64 + lane];
        float u4 = h3[(size_t)p4.x * 64 + lane];
        float u5 = h3[(size_t)p5.x * 64 + lane];
        float u6 = h3[(size_t)p6.x * 64 + lane];
        float u7 = h3[(size_t)p7.x * 64 + lane];
        acc += __int_as_float(p0.y) * u0 + __int_as_float(p1.y) * u1 +
               __int_as_float(p2.y) * u2 + __int_as_float(p3.y) * u3 +
               __int_as_float(p4.y) * u4 + __int_as_float(p5.y) * u5 +
               __int_as_float(p6.y) * u6 + __int_as_float(p7.y) * u7;
    }
    for (; e < end; e++) {
        int2 p = eS[e];
        acc += __int_as_float(p.y) * h3[(size_t)p.x * 64 + lane];
    }
    out[(size_t)g * 64 + lane] = acc + b2[lane];
}

extern "C" void kernel_launch(void* const* d_in, const int* in_sizes, int n_in,
                              void* d_out, int out_size, void* d_ws, size_t ws_size,
                              hipStream_t stream) {
    const float* x  = (const float*)d_in[0];
    const int*   ei = (const int*)d_in[1];
    const float* W1 = (const float*)d_in[2];
    const float* b1 = (const float*)d_in[3];
    const float* W2 = (const float*)d_in[4];
    const float* b2 = (const float*)d_in[5];
    float* out = (float*)d_out;

    const int n = in_sizes[0] / 128;   // 100000
    const int E = in_sizes[1] / 2;     // 1600000
    const int* src = ei;
    const int* dst = ei + E;
    const int nb = (n + 255) / 256;

    char* ws = (char*)d_ws;
    size_t off = 0;
    auto carve = [&](size_t bytes) -> char* {
        char* p = ws + off;
        off += (bytes + 255) & ~(size_t)255;
        return p;
    };
    int*   deg        = (int*)carve((size_t)n * 4);
    float* dinv       = (float*)carve((size_t)n * 4);
    int*   rowstart   = (int*)carve((size_t)n * 4);
    int*   cursor     = (int*)carve((size_t)n * 4);
    int*   blockSums  = (int*)carve((size_t)nb * 4);
    int2*  edgeSorted = (int2*)carve((size_t)E * 8);
    float* bufA       = (float*)carve((size_t)n * 128 * 4);  // h1, then h3
    float* bufB       = (float*)carve((size_t)n * 128 * 4);  // h2

    hipMemsetAsync(deg, 0, (size_t)n * 4, stream);

    deg_kernel<<<(E + 255) / 256, 256, 0, stream>>>(dst, deg, E);
    scan1_kernel<<<nb, 256, 0, stream>>>(deg, rowstart, blockSums, dinv, n);
    scan2_kernel<<<1, 512, 0, stream>>>(blockSums, nb);
    scan3_kernel<<<(n + 255) / 256, 256, 0, stream>>>(rowstart, blockSums, cursor, n);
    sort_kernel<<<(E + 255) / 256, 256, 0, stream>>>(src, dst, dinv, cursor, edgeSorted, E);

    // layer 1: h1 = x@W1 ; h2 = relu(agg(h1) + b1)
    gemm_nk128<<<(n + 63) / 64, 256, 0, stream>>>(x, W1, bufA, n);
    gather1_kernel<<<(n + 3) / 4, 256, 0, stream>>>(edgeSorted, rowstart, deg, dinv,
                                                    bufA, b1, bufB, n);

    // layer 2: h3 = h2@W2 (reuse bufA) ; out = agg(h3) + b2
    gemm_nk64<<<(n + 31) / 32, 256, 0, stream>>>(bufB, W2, bufA, n);
    gather2_kernel<<<(n + 3) / 4, 256, 0, stream>>>(edgeSorted, rowstart, deg, dinv,
                                                    bufA, b2, out, n);
}

// Round 7
// 560.822 us; speedup vs baseline: 2.0271x; 2.0271x over previous
//
#include <hip/hip_runtime.h>

// ---------------- degree ----------------
__global__ void deg_kernel(const int* __restrict__ dst, int* __restrict__ deg, int E) {
    int e = blockIdx.x * blockDim.x + threadIdx.x;
    if (e < E) atomicAdd(&deg[dst[e]], 1);
}

// ---------------- scan1 (+ fused dinv) ----------------
__global__ void scan1_kernel(const int* __restrict__ deg, int* __restrict__ rowstart,
                             int* __restrict__ blockSums, float* __restrict__ dinv, int n) {
    __shared__ int tmp[256];
    int t = threadIdx.x;
    int i = blockIdx.x * 256 + t;
    int v = (i < n) ? deg[i] : 0;
    if (i < n) dinv[i] = rsqrtf((float)(v + 1));  // +1 = self loop
    tmp[t] = v;
    __syncthreads();
#pragma unroll
    for (int off = 1; off < 256; off <<= 1) {
        int add = (t >= off) ? tmp[t - off] : 0;
        __syncthreads();
        tmp[t] += add;
        __syncthreads();
    }
    if (i < n) rowstart[i] = tmp[t] - v;
    if (t == 255) blockSums[blockIdx.x] = tmp[255];
}

__global__ void scan2_kernel(int* __restrict__ blockSums, int nb) {
    __shared__ int tmp[512];
    int t = threadIdx.x;
    int v = (t < nb) ? blockSums[t] : 0;
    tmp[t] = v;
    __syncthreads();
#pragma unroll
    for (int off = 1; off < 512; off <<= 1) {
        int add = (t >= off) ? tmp[t - off] : 0;
        __syncthreads();
        tmp[t] += add;
        __syncthreads();
    }
    if (t < nb) blockSums[t] = tmp[t] - v;
}

__global__ void scan3_kernel(int* __restrict__ rowstart, const int* __restrict__ blockSums,
                             int* __restrict__ cursor, int n) {
    int i = blockIdx.x * blockDim.x + threadIdx.x;
    if (i < n) {
        int r = rowstart[i] + blockSums[i >> 8];
        rowstart[i] = r;
        cursor[i] = r;
    }
}

// ---------------- counting-sort edges by dst; pack (src, weight) ----------------
__global__ void sort_kernel(const int* __restrict__ src, const int* __restrict__ dst,
                            const float* __restrict__ dinv, int* __restrict__ cursor,
                            int2* __restrict__ edgeSorted, int E) {
    int e = blockIdx.x * blockDim.x + threadIdx.x;
    if (e < E) {
        int s = src[e], d = dst[e];
        int pos = atomicAdd(&cursor[d], 1);
        int2 p;
        p.x = s;
        p.y = __float_as_int(dinv[s] * dinv[d]);
        edgeSorted[pos] = p;
    }
}

// ---------------- GEMM1: h1[N,128] = x[N,128] @ W1[128,128] ----------------
// 256 threads, tile 64 nodes x 128 cols, register tile 8x4, k-step 4
// (unchanged from R5/R6 — not implicated in the R6 regression)
__global__ __launch_bounds__(256) void gemm_nk128(const float* __restrict__ x,
                                                  const float* __restrict__ W,
                                                  float* __restrict__ h, int n) {
    __shared__ float xs[64][128];
    int t = threadIdx.x;
    int node0 = blockIdx.x * 64;
#pragma unroll
    for (int i = 0; i < 8; i++) {
        int fi = t + 256 * i;            // 0..2047 float4 slots
        int row = fi >> 5, cv = fi & 31;
        float4 v = make_float4(0.f, 0.f, 0.f, 0.f);
        if (node0 + row < n) v = ((const float4*)x)[(size_t)(node0 + row) * 32 + cv];
        ((float4*)(&xs[0][0]))[fi] = v;
    }
    __syncthreads();

    int tx = t & 31, ty = t >> 5;
    int c0 = tx * 4;
    float acc[8][4];
#pragma unroll
    for (int i = 0; i < 8; i++)
#pragma unroll
        for (int j = 0; j < 4; j++) acc[i][j] = 0.f;

    for (int k = 0; k < 128; k += 4) {
        float4 w0 = *(const float4*)(W + (k + 0) * 128 + c0);
        float4 w1 = *(const float4*)(W + (k + 1) * 128 + c0);
        float4 w2 = *(const float4*)(W + (k + 2) * 128 + c0);
        float4 w3 = *(const float4*)(W + (k + 3) * 128 + c0);
#pragma unroll
        for (int i = 0; i < 8; i++) {
            float4 xv = *(const float4*)(&xs[ty + 8 * i][k]);
            acc[i][0] += xv.x * w0.x + xv.y * w1.x + xv.z * w2.x + xv.w * w3.x;
            acc[i][1] += xv.x * w0.y + xv.y * w1.y + xv.z * w2.y + xv.w * w3.y;
            acc[i][2] += xv.x * w0.z + xv.y * w1.z + xv.z * w2.z + xv.w * w3.z;
            acc[i][3] += xv.x * w0.w + xv.y * w1.w + xv.z * w2.w + xv.w * w3.w;
        }
    }
#pragma unroll
    for (int i = 0; i < 8; i++) {
        int node = node0 + ty + 8 * i;
        if (node < n)
            *(float4*)(h + (size_t)node * 128 + c0) =
                make_float4(acc[i][0], acc[i][1], acc[i][2], acc[i][3]);
    }
}

// ---------------- gather1: h2 = relu(agg(h1) + b1) ----------------
// one wave per node (lane = 2 cols, float2), 4 nodes/block, no barrier; 8x unroll
__global__ __launch_bounds__(256) void gather1_kernel(
        const int2* __restrict__ eS, const int* __restrict__ rowstart,
        const int* __restrict__ deg, const float* __restrict__ dinv,
        const float* __restrict__ h1, const float* __restrict__ b1,
        float* __restrict__ h2, int n) {
    int t = threadIdx.x;
    int w = t >> 6, lane = t & 63;
    int g = blockIdx.x * 4 + w;
    if (g >= n) return;

    float di = dinv[g];
    float w0 = di * di;
    float2 v = ((const float2*)(h1 + (size_t)g * 128))[lane];
    float2 acc = make_float2(w0 * v.x, w0 * v.y);
    int beg = rowstart[g], end = beg + deg[g];
    int e = beg;
    for (; e + 8 <= end; e += 8) {
        int2 p0 = eS[e], p1 = eS[e+1], p2 = eS[e+2], p3 = eS[e+3];
        int2 p4 = eS[e+4], p5 = eS[e+5], p6 = eS[e+6], p7 = eS[e+7];
        float2 u0 = ((const float2*)(h1 + (size_t)p0.x * 128))[lane];
        float2 u1 = ((const float2*)(h1 + (size_t)p1.x * 128))[lane];
        float2 u2 = ((const float2*)(h1 + (size_t)p2.x * 128))[lane];
        float2 u3 = ((const float2*)(h1 + (size_t)p3.x * 128))[lane];
        float2 u4 = ((const float2*)(h1 + (size_t)p4.x * 128))[lane];
        float2 u5 = ((const float2*)(h1 + (size_t)p5.x * 128))[lane];
        float2 u6 = ((const float2*)(h1 + (size_t)p6.x * 128))[lane];
        float2 u7 = ((const float2*)(h1 + (size_t)p7.x * 128))[lane];
        acc.x += __int_as_float(p0.y) * u0.x; acc.y += __int_as_float(p0.y) * u0.y;
        acc.x += __int_as_float(p1.y) * u1.x; acc.y += __int_as_float(p1.y) * u1.y;
        acc.x += __int_as_float(p2.y) * u2.x; acc.y += __int_as_float(p2.y) * u2.y;
        acc.x += __int_as_float(p3.y) * u3.x; acc.y += __int_as_float(p3.y) * u3.y;
        acc.x += __int_as_float(p4.y) * u4.x; acc.y += __int_as_float(p4.y) * u4.y;
        acc.x += __int_as_float(p5.y) * u5.x; acc.y += __int_as_float(p5.y) * u5.y;
        acc.x += __int_as_float(p6.y) * u6.x; acc.y += __int_as_float(p6.y) * u6.y;
        acc.x += __int_as_float(p7.y) * u7.x; acc.y += __int_as_float(p7.y) * u7.y;
    }
    for (; e < end; e++) {
        int2 p = eS[e];
        float2 u = ((const float2*)(h1 + (size_t)p.x * 128))[lane];
        float wf = __int_as_float(p.y);
        acc.x += wf * u.x; acc.y += wf * u.y;
    }
    float2 b = ((const float2*)b1)[lane];
    acc.x = fmaxf(acc.x + b.x, 0.f);
    acc.y = fmaxf(acc.y + b.y, 0.f);
    ((float2*)(h2 + (size_t)g * 128))[lane] = acc;
}

// ---------------- GEMM2: h3[N,64] = h2[N,128] @ W2[128,64] ----------------
// R4-proven shape: k-step 1, scalar LDS reads, one float4 W load per k.
// VGPR ~32, high occupancy. (R6's k-step-4 version hit VGPR=256 / 0.4% occupancy.)
__global__ __launch_bounds__(256) void gemm_nk64(const float* __restrict__ x,
                                                 const float* __restrict__ W,
                                                 float* __restrict__ h, int n) {
    __shared__ float xs[32][128];
    int t = threadIdx.x;
    int node0 = blockIdx.x * 32;
#pragma unroll
    for (int i = 0; i < 4; i++) {
        int fi = t + 256 * i;
        int row = fi >> 5, cv = fi & 31;
        float4 v = make_float4(0.f, 0.f, 0.f, 0.f);
        if (node0 + row < n) v = ((const float4*)x)[(size_t)(node0 + row) * 32 + cv];
        ((float4*)(&xs[0][0]))[fi] = v;
    }
    __syncthreads();

    int tx = t & 15, ty = t >> 4;
    int c0 = tx * 4;
    float acc[2][4];
#pragma unroll
    for (int i = 0; i < 2; i++)
#pragma unroll
        for (int j = 0; j < 4; j++) acc[i][j] = 0.f;

    for (int k = 0; k < 128; k++) {
        float4 w = *(const float4*)(W + k * 64 + c0);
#pragma unroll
        for (int i = 0; i < 2; i++) {
            float xval = xs[ty + 16 * i][k];
            acc[i][0] += xval * w.x;
            acc[i][1] += xval * w.y;
            acc[i][2] += xval * w.z;
            acc[i][3] += xval * w.w;
        }
    }
#pragma unroll
    for (int i = 0; i < 2; i++) {
        int node = node0 + ty + 16 * i;
        if (node < n)
            *(float4*)(h + (size_t)node * 64 + c0) =
                make_float4(acc[i][0], acc[i][1], acc[i][2], acc[i][3]);
    }
}

// ---------------- gather2: out = agg(h3) + b2 ; one wave per node, lane = col ----------------
__global__ __launch_bounds__(256) void gather2_kernel(
        const int2* __restrict__ eS, const int* __restrict__ rowstart,
        const int* __restrict__ deg, const float* __restrict__ dinv,
        const float* __restrict__ h3, const float* __restrict__ b2,
        float* __restrict__ out, int n) {
    int t = threadIdx.x;
    int w = t >> 6, lane = t & 63;
    int g = blockIdx.x * 4 + w;
    if (g >= n) return;
    float di = dinv[g];
    float w0 = di * di;
    float acc = w0 * h3[(size_t)g * 64 + lane];
    int beg = rowstart[g], end = beg + deg[g];
    int e = beg;
    for (; e + 8 <= end; e += 8) {
        int2 p0 = eS[e], p1 = eS[e+1], p2 = eS[e+2], p3 = eS[e+3];
        int2 p4 = eS[e+4], p5 = eS[e+5], p6 = eS[e+6], p7 = eS[e+7];
        float u0 = h3[(size_t)p0.x * 64 + lane];
        float u1 = h3[(size_t)p1.x * 64 + lane];
        float u2 = h3[(size_t)p2.x * 64 + lane];
        float u3 = h3[(size_t)p3.x * 64 + lane];
        float u4 = h3[(size_t)p4.x * 64 + lane];
        float u5 = h3[(size_t)p5.x * 64 + lane];
        float u6 = h3[(size_t)p6.x * 64 + lane];
        float u7 = h3[(size_t)p7.x * 64 + lane];
        acc += __int_as_float(p0.y) * u0 + __int_as_float(p1.y) * u1 +
               __int_as_float(p2.y) * u2 + __int_as_float(p3.y) * u3 +
               __int_as_float(p4.y) * u4 + __int_as_float(p5.y) * u5 +
               __int_as_float(p6.y) * u6 + __int_as_float(p7.y) * u7;
    }
    for (; e < end; e++) {
        int2 p = eS[e];
        acc += __int_as_float(p.y) * h3[(size_t)p.x * 64 + lane];
    }
    out[(size_t)g * 64 + lane] = acc + b2[lane];
}

extern "C" void kernel_launch(void* const* d_in, const int* in_sizes, int n_in,
                              void* d_out, int out_size, void* d_ws, size_t ws_size,
                              hipStream_t stream) {
    const float* x  = (const float*)d_in[0];
    const int*   ei = (const int*)d_in[1];
    const float* W1 = (const float*)d_in[2];
    const float* b1 = (const float*)d_in[3];
    const float* W2 = (const float*)d_in[4];
    const float* b2 = (const float*)d_in[5];
    float* out = (float*)d_out;

    const int n = in_sizes[0] / 128;   // 100000
    const int E = in_sizes[1] / 2;     // 1600000
    const int* src = ei;
    const int* dst = ei + E;
    const int nb = (n + 255) / 256;

    char* ws = (char*)d_ws;
    size_t off = 0;
    auto carve = [&](size_t bytes) -> char* {
        char* p = ws + off;
        off += (bytes + 255) & ~(size_t)255;
        return p;
    };
    int*   deg        = (int*)carve((size_t)n * 4);
    float* dinv       = (float*)carve((size_t)n * 4);
    int*   rowstart   = (int*)carve((size_t)n * 4);
    int*   cursor     = (int*)carve((size_t)n * 4);
    int*   blockSums  = (int*)carve((size_t)nb * 4);
    int2*  edgeSorted = (int2*)carve((size_t)E * 8);
    float* bufA       = (float*)carve((size_t)n * 128 * 4);  // h1, then h3
    float* bufB       = (float*)carve((size_t)n * 128 * 4);  // h2

    hipMemsetAsync(deg, 0, (size_t)n * 4, stream);

    deg_kernel<<<(E + 255) / 256, 256, 0, stream>>>(dst, deg, E);
    scan1_kernel<<<nb, 256, 0, stream>>>(deg, rowstart, blockSums, dinv, n);
    scan2_kernel<<<1, 512, 0, stream>>>(blockSums, nb);
    scan3_kernel<<<(n + 255) / 256, 256, 0, stream>>>(rowstart, blockSums, cursor, n);
    sort_kernel<<<(E + 255) / 256, 256, 0, stream>>>(src, dst, dinv, cursor, edgeSorted, E);

    // layer 1: h1 = x@W1 ; h2 = relu(agg(h1) + b1)
    gemm_nk128<<<(n + 63) / 64, 256, 0, stream>>>(x, W1, bufA, n);
    gather1_kernel<<<(n + 3) / 4, 256, 0, stream>>>(edgeSorted, rowstart, deg, dinv,
                                                    bufA, b1, bufB, n);

    // layer 2: h3 = h2@W2 (reuse bufA) ; out = agg(h3) + b2
    gemm_nk64<<<(n + 31) / 32, 256, 0, stream>>>(bufB, W2, bufA, n);
    gather2_kernel<<<(n + 3) / 4, 256, 0, stream>>>(edgeSorted, rowstart, deg, dinv,
                                                    bufA, b2, out, n);
}

// Round 8
// 524.926 us; speedup vs baseline: 2.1657x; 1.0684x over previous
//
#include <hip/hip_runtime.h>

// ---------------- degree ----------------
__global__ void deg_kernel(const int* __restrict__ dst, int* __restrict__ deg, int E) {
    int e = blockIdx.x * blockDim.x + threadIdx.x;
    if (e < E) atomicAdd(&deg[dst[e]], 1);
}

// ---------------- scan1 (+ fused dinv) ----------------
__global__ void scan1_kernel(const int* __restrict__ deg, int* __restrict__ rowstart,
                             int* __restrict__ blockSums, float* __restrict__ dinv, int n) {
    __shared__ int tmp[256];
    int t = threadIdx.x;
    int i = blockIdx.x * 256 + t;
    int v = (i < n) ? deg[i] : 0;
    if (i < n) dinv[i] = rsqrtf((float)(v + 1));  // +1 = self loop
    tmp[t] = v;
    __syncthreads();
#pragma unroll
    for (int off = 1; off < 256; off <<= 1) {
        int add = (t >= off) ? tmp[t - off] : 0;
        __syncthreads();
        tmp[t] += add;
        __syncthreads();
    }
    if (i < n) rowstart[i] = tmp[t] - v;
    if (t == 255) blockSums[blockIdx.x] = tmp[255];
}

__global__ void scan2_kernel(int* __restrict__ blockSums, int nb) {
    __shared__ int tmp[512];
    int t = threadIdx.x;
    int v = (t < nb) ? blockSums[t] : 0;
    tmp[t] = v;
    __syncthreads();
#pragma unroll
    for (int off = 1; off < 512; off <<= 1) {
        int add = (t >= off) ? tmp[t - off] : 0;
        __syncthreads();
        tmp[t] += add;
        __syncthreads();
    }
    if (t < nb) blockSums[t] = tmp[t] - v;
}

__global__ void scan3_kernel(int* __restrict__ rowstart, const int* __restrict__ blockSums,
                             int* __restrict__ cursor, int n) {
    int i = blockIdx.x * blockDim.x + threadIdx.x;
    if (i < n) {
        int r = rowstart[i] + blockSums[i >> 8];
        rowstart[i] = r;
        cursor[i] = r;
    }
}

// ---------------- fused: counting-sort (4B payload)  |  GEMM1 ----------------
// Independent work overlapped in one launch. Every 5th block is a GEMM block
// (sortBlocks ~ 4x gemmBlocks), so both kinds co-reside on each CU.
__global__ __launch_bounds__(256) void sort_gemm1_kernel(
        const int* __restrict__ src, const int* __restrict__ dst,
        int* __restrict__ cursor, int* __restrict__ srcSorted, int E,
        const float* __restrict__ x, const float* __restrict__ W,
        float* __restrict__ h, int n) {
    __shared__ float xs[64][128];
    int bid = blockIdx.x;
    int t = threadIdx.x;
    if (bid % 5 == 0) {
        // ---- GEMM1: 64-node x 128-col tile, reg tile 8x4, k-step 4 ----
        int node0 = (bid / 5) * 64;
#pragma unroll
        for (int i = 0; i < 8; i++) {
            int fi = t + 256 * i;            // float4 slots
            int row = fi >> 5, cv = fi & 31;
            float4 v = make_float4(0.f, 0.f, 0.f, 0.f);
            if (node0 + row < n) v = ((const float4*)x)[(size_t)(node0 + row) * 32 + cv];
            ((float4*)(&xs[0][0]))[fi] = v;
        }
        __syncthreads();

        int tx = t & 31, ty = t >> 5;
        int c0 = tx * 4;
        float acc[8][4];
#pragma unroll
        for (int i = 0; i < 8; i++)
#pragma unroll
            for (int j = 0; j < 4; j++) acc[i][j] = 0.f;

        for (int k = 0; k < 128; k += 4) {
            float4 w0 = *(const float4*)(W + (k + 0) * 128 + c0);
            float4 w1 = *(const float4*)(W + (k + 1) * 128 + c0);
            float4 w2 = *(const float4*)(W + (k + 2) * 128 + c0);
            float4 w3 = *(const float4*)(W + (k + 3) * 128 + c0);
#pragma unroll
            for (int i = 0; i < 8; i++) {
                float4 xv = *(const float4*)(&xs[ty + 8 * i][k]);
                acc[i][0] += xv.x * w0.x + xv.y * w1.x + xv.z * w2.x + xv.w * w3.x;
                acc[i][1] += xv.x * w0.y + xv.y * w1.y + xv.z * w2.y + xv.w * w3.y;
                acc[i][2] += xv.x * w0.z + xv.y * w1.z + xv.z * w2.z + xv.w * w3.z;
                acc[i][3] += xv.x * w0.w + xv.y * w1.w + xv.z * w2.w + xv.w * w3.w;
            }
        }
#pragma unroll
        for (int i = 0; i < 8; i++) {
            int node = node0 + ty + 8 * i;
            if (node < n)
                *(float4*)(h + (size_t)node * 128 + c0) =
                    make_float4(acc[i][0], acc[i][1], acc[i][2], acc[i][3]);
        }
    } else {
        // ---- counting sort: one edge per thread, 4B payload ----
        int sb = (bid / 5) * 4 + (bid % 5) - 1;
        int e = sb * 256 + t;
        if (e < E) {
            int s = src[e], d = dst[e];
            int pos = atomicAdd(&cursor[d], 1);
            srcSorted[pos] = s;
        }
    }
}

// ---------------- gather1: h2 = relu(agg(h1) + b1) ----------------
// one wave per node (lane = 2 cols, float2); weights recomputed from dinv
__global__ __launch_bounds__(256) void gather1_kernel(
        const int* __restrict__ srcS, const int* __restrict__ rowstart,
        const int* __restrict__ deg, const float* __restrict__ dinv,
        const float* __restrict__ h1, const float* __restrict__ b1,
        float* __restrict__ h2, int n) {
    int t = threadIdx.x;
    int g = __builtin_amdgcn_readfirstlane(blockIdx.x * 4 + (t >> 6));
    int lane = t & 63;
    if (g >= n) return;

    float dg = dinv[g];
    float2 v = ((const float2*)(h1 + (size_t)g * 128))[lane];
    float2 acc = make_float2(dg * dg * v.x, dg * dg * v.y);
    int beg = rowstart[g], end = beg + deg[g];
    int e = beg;
    for (; e + 8 <= end; e += 8) {
        int s0 = srcS[e+0], s1 = srcS[e+1], s2 = srcS[e+2], s3 = srcS[e+3];
        int s4 = srcS[e+4], s5 = srcS[e+5], s6 = srcS[e+6], s7 = srcS[e+7];
        float2 u0 = ((const float2*)(h1 + (size_t)s0 * 128))[lane];
        float2 u1 = ((const float2*)(h1 + (size_t)s1 * 128))[lane];
        float2 u2 = ((const float2*)(h1 + (size_t)s2 * 128))[lane];
        float2 u3 = ((const float2*)(h1 + (size_t)s3 * 128))[lane];
        float2 u4 = ((const float2*)(h1 + (size_t)s4 * 128))[lane];
        float2 u5 = ((const float2*)(h1 + (size_t)s5 * 128))[lane];
        float2 u6 = ((const float2*)(h1 + (size_t)s6 * 128))[lane];
        float2 u7 = ((const float2*)(h1 + (size_t)s7 * 128))[lane];
        float w0 = dinv[s0] * dg, w1 = dinv[s1] * dg, w2 = dinv[s2] * dg, w3 = dinv[s3] * dg;
        float w4 = dinv[s4] * dg, w5 = dinv[s5] * dg, w6 = dinv[s6] * dg, w7 = dinv[s7] * dg;
        acc.x += w0 * u0.x; acc.y += w0 * u0.y;
        acc.x += w1 * u1.x; acc.y += w1 * u1.y;
        acc.x += w2 * u2.x; acc.y += w2 * u2.y;
        acc.x += w3 * u3.x; acc.y += w3 * u3.y;
        acc.x += w4 * u4.x; acc.y += w4 * u4.y;
        acc.x += w5 * u5.x; acc.y += w5 * u5.y;
        acc.x += w6 * u6.x; acc.y += w6 * u6.y;
        acc.x += w7 * u7.x; acc.y += w7 * u7.y;
    }
    for (; e < end; e++) {
        int s = srcS[e];
        float2 u = ((const float2*)(h1 + (size_t)s * 128))[lane];
        float wf = dinv[s] * dg;
        acc.x += wf * u.x; acc.y += wf * u.y;
    }
    float2 b = ((const float2*)b1)[lane];
    acc.x = fmaxf(acc.x + b.x, 0.f);
    acc.y = fmaxf(acc.y + b.y, 0.f);
    ((float2*)(h2 + (size_t)g * 128))[lane] = acc;
}

// ---------------- GEMM2: h3[N,64] = h2[N,128] @ W2[128,64] ----------------
// k-step 1, scalar LDS reads (VGPR ~32, high occupancy — proven R4 shape)
__global__ __launch_bounds__(256) void gemm_nk64(const float* __restrict__ x,
                                                 const float* __restrict__ W,
                                                 float* __restrict__ h, int n) {
    __shared__ float xs[32][128];
    int t = threadIdx.x;
    int node0 = blockIdx.x * 32;
#pragma unroll
    for (int i = 0; i < 4; i++) {
        int fi = t + 256 * i;
        int row = fi >> 5, cv = fi & 31;
        float4 v = make_float4(0.f, 0.f, 0.f, 0.f);
        if (node0 + row < n) v = ((const float4*)x)[(size_t)(node0 + row) * 32 + cv];
        ((float4*)(&xs[0][0]))[fi] = v;
    }
    __syncthreads();

    int tx = t & 15, ty = t >> 4;
    int c0 = tx * 4;
    float acc[2][4];
#pragma unroll
    for (int i = 0; i < 2; i++)
#pragma unroll
        for (int j = 0; j < 4; j++) acc[i][j] = 0.f;

    for (int k = 0; k < 128; k++) {
        float4 w = *(const float4*)(W + k * 64 + c0);
#pragma unroll
        for (int i = 0; i < 2; i++) {
            float xval = xs[ty + 16 * i][k];
            acc[i][0] += xval * w.x;
            acc[i][1] += xval * w.y;
            acc[i][2] += xval * w.z;
            acc[i][3] += xval * w.w;
        }
    }
#pragma unroll
    for (int i = 0; i < 2; i++) {
        int node = node0 + ty + 16 * i;
        if (node < n)
            *(float4*)(h + (size_t)node * 64 + c0) =
                make_float4(acc[i][0], acc[i][1], acc[i][2], acc[i][3]);
    }
}

// ---------------- gather2: out = agg(h3) + b2 ; one wave per node, lane = col ----------------
__global__ __launch_bounds__(256) void gather2_kernel(
        const int* __restrict__ srcS, const int* __restrict__ rowstart,
        const int* __restrict__ deg, const float* __restrict__ dinv,
        const float* __restrict__ h3, const float* __restrict__ b2,
        float* __restrict__ out, int n) {
    int t = threadIdx.x;
    int g = __builtin_amdgcn_readfirstlane(blockIdx.x * 4 + (t >> 6));
    int lane = t & 63;
    if (g >= n) return;
    float dg = dinv[g];
    float acc = dg * dg * h3[(size_t)g * 64 + lane];
    int beg = rowstart[g], end = beg + deg[g];
    int e = beg;
    for (; e + 8 <= end; e += 8) {
        int s0 = srcS[e+0], s1 = srcS[e+1], s2 = srcS[e+2], s3 = srcS[e+3];
        int s4 = srcS[e+4], s5 = srcS[e+5], s6 = srcS[e+6], s7 = srcS[e+7];
        float u0 = h3[(size_t)s0 * 64 + lane];
        float u1 = h3[(size_t)s1 * 64 + lane];
        float u2 = h3[(size_t)s2 * 64 + lane];
        float u3 = h3[(size_t)s3 * 64 + lane];
        float u4 = h3[(size_t)s4 * 64 + lane];
        float u5 = h3[(size_t)s5 * 64 + lane];
        float u6 = h3[(size_t)s6 * 64 + lane];
        float u7 = h3[(size_t)s7 * 64 + lane];
        acc += dinv[s0] * dg * u0 + dinv[s1] * dg * u1 +
               dinv[s2] * dg * u2 + dinv[s3] * dg * u3 +
               dinv[s4] * dg * u4 + dinv[s5] * dg * u5 +
               dinv[s6] * dg * u6 + dinv[s7] * dg * u7;
    }
    for (; e < end; e++) {
        int s = srcS[e];
        acc += dinv[s] * dg * h3[(size_t)s * 64 + lane];
    }
    out[(size_t)g * 64 + lane] = acc + b2[lane];
}

extern "C" void kernel_launch(void* const* d_in, const int* in_sizes, int n_in,
                              void* d_out, int out_size, void* d_ws, size_t ws_size,
                              hipStream_t stream) {
    const float* x  = (const float*)d_in[0];
    const int*   ei = (const int*)d_in[1];
    const float* W1 = (const float*)d_in[2];
    const float* b1 = (const float*)d_in[3];
    const float* W2 = (const float*)d_in[4];
    const float* b2 = (const float*)d_in[5];
    float* out = (float*)d_out;

    const int n = in_sizes[0] / 128;   // 100000
    const int E = in_sizes[1] / 2;     // 1600000
    const int* src = ei;
    const int* dst = ei + E;
    const int nb = (n + 255) / 256;

    char* ws = (char*)d_ws;
    size_t off = 0;
    auto carve = [&](size_t bytes) -> char* {
        char* p = ws + off;
        off += (bytes + 255) & ~(size_t)255;
        return p;
    };
    int*   deg       = (int*)carve((size_t)n * 4);
    float* dinv      = (float*)carve((size_t)n * 4);
    int*   rowstart  = (int*)carve((size_t)n * 4);
    int*   cursor    = (int*)carve((size_t)n * 4);
    int*   blockSums = (int*)carve((size_t)nb * 4);
    int*   srcSorted = (int*)carve((size_t)E * 4);
    float* bufA      = (float*)carve((size_t)n * 128 * 4);  // h1, then h3
    float* bufB      = (float*)carve((size_t)n * 128 * 4);  // h2

    hipMemsetAsync(deg, 0, (size_t)n * 4, stream);

    deg_kernel<<<(E + 255) / 256, 256, 0, stream>>>(dst, deg, E);
    scan1_kernel<<<nb, 256, 0, stream>>>(deg, rowstart, blockSums, dinv, n);
    scan2_kernel<<<1, 512, 0, stream>>>(blockSums, nb);
    scan3_kernel<<<(n + 255) / 256, 256, 0, stream>>>(rowstart, blockSums, cursor, n);

    // fused sort | gemm1 (independent work, interleaved 1:4)
    int gemmBlocks = (n + 63) / 64;
    int sortBlocks = (E + 255) / 256;
    int G1 = ((sortBlocks + 3) / 4) * 5;
    int G2 = gemmBlocks * 5;
    int G = (G1 > G2) ? G1 : G2;
    sort_gemm1_kernel<<<G, 256, 0, stream>>>(src, dst, cursor, srcSorted, E,
                                             x, W1, bufA, n);

    // layer 1 aggregation: h2 = relu(agg(h1) + b1)
    gather1_kernel<<<(n + 3) / 4, 256, 0, stream>>>(srcSorted, rowstart, deg, dinv,
                                                    bufA, b1, bufB, n);

    // layer 2: h3 = h2@W2 (reuse bufA) ; out = agg(h3) + b2
    gemm_nk64<<<(n + 31) / 32, 256, 0, stream>>>(bufB, W2, bufA, n);
    gather2_kernel<<<(n + 3) / 4, 256, 0, stream>>>(srcSorted, rowstart, deg, dinv,
                                                    bufA, b2, out, n);
}